// Round 8
// baseline (113.155 us; speedup 1.0000x reference)
//
#include <hip/hip_runtime.h>

// StructureTensorEffect: B=4, C=3, H=W=1024, fp32.
// Round 14: register-batched LDS reads (MLP restructure). Evidence
// through R13: six structures all 41-45us; VALUBusy 21% x 42us = 8.8us
// matches the honest VALU work content EXACTLY -> VALU runs at full
// content but 21% duty cycle; DS/stores/staging all << 42us; nothing
// saturates. Regime = dependency-stall-dominated: per tile-wave the
// body does 36x {5 ds_read -> lgkm wait (~120cy) -> ~25 VALU} with only
// 2 blocks/CU (LDS-capped) to cross-cover. R13's counted-vmcnt pipeline
// fixed cross-tile staging (~1us); the untouched variable is in-wave
// LDS-read MLP. This round: per channel, load ALL RW x 5 taps into a
// fully-unrolled register array FIRST (compile-time indices only), then
// compute -- 3 stall points/tile instead of 36, reads at throughput
// (~5.8cy) not latency (~120cy). VGPR +60-80 is FREE: LDS 73.9KB caps
// at 2 blocks/CU regardless -> __launch_bounds__(256,1) releases the
// allocator. Skeleton (pipeline/staging/stores/border) = R13 verbatim.
// Borders: R4-proven scheme (store mask + border slice, dispatched first).

#define W_ 1024
#define H_ 1024
#define PLANE (1 << 20)
#define TCOLS 64
#define TROWS 32
#define ROWS 8
#define LSTRIDE 72     // staged cols: x0-4 .. x0+67 (18 float4 groups)
#define NTILES 4       // tiles (y-bands) per persistent block
#define BUFSZ 9232     // floats: 3*38*72 = 8208 (worst-case IP=2) + 1024 pad

__device__ __forceinline__ float lerp1(float a, float b, float f) {
    return fmaf(f, b - a, a);
}

// async 16B global->LDS copy (gfx950). Dest must be linear in lane order.
__device__ __forceinline__ void async_copy16(const float* g, float* s) {
    __builtin_amdgcn_global_load_lds(
        (const __attribute__((address_space(1))) unsigned int*)g,
        (__attribute__((address_space(3))) unsigned int*)s,
        16, 0, 0);
}

// Exact per-pixel reference path (any sigma, any border) — verified R1-R13.
__device__ void slow_pixel(const float* __restrict__ Xb, float* __restrict__ Ob,
                           float sg, int xi, int y)
{
    float imf = floorf(-sg), ipf = floorf(sg);
    float fm  = -sg - imf;
    float fp  =  sg - ipf;
    int   im  = (int)imf, ip = (int)ipf;

    int cm0 = min(max(xi + im, 0), W_ - 1), cm1 = min(cm0 + 1, W_ - 1);
    int cp0 = min(max(xi + ip, 0), W_ - 1), cp1 = min(cp0 + 1, W_ - 1);
    int rm0 = min(max(y + im, 0), H_ - 1),  rm1 = min(rm0 + 1, H_ - 1);
    int rp0 = min(max(y + ip, 0), H_ - 1),  rp1 = min(rp0 + 1, H_ - 1);

    int o_rm0 = rm0 << 10, o_rm1 = rm1 << 10;
    int o_rp0 = rp0 << 10, o_rp1 = rp1 << 10;
    int o_r0  = y   << 10;

    float oxx = 0.f, oyy = 0.f, oxy = 0.f;

    #pragma unroll
    for (int c = 0; c < 3; ++c) {
        const float* base = Xb + ((size_t)c << 20);

        float hm_m0 = lerp1(base[o_rm0 + cm0], base[o_rm0 + cm1], fm);
        float hm_m1 = lerp1(base[o_rm1 + cm0], base[o_rm1 + cm1], fm);
        float hm_0  = lerp1(base[o_r0  + cm0], base[o_r0  + cm1], fm);
        float hm_p0 = lerp1(base[o_rp0 + cm0], base[o_rp0 + cm1], fm);
        float hm_p1 = lerp1(base[o_rp1 + cm0], base[o_rp1 + cm1], fm);
        float hp_m0 = lerp1(base[o_rm0 + cp0], base[o_rm0 + cp1], fp);
        float hp_m1 = lerp1(base[o_rm1 + cp0], base[o_rm1 + cp1], fp);
        float hp_0  = lerp1(base[o_r0  + cp0], base[o_r0  + cp1], fp);
        float hp_p0 = lerp1(base[o_rp0 + cp0], base[o_rp0 + cp1], fp);
        float hp_p1 = lerp1(base[o_rp1 + cp0], base[o_rp1 + cp1], fp);
        float h0_m0 = base[o_rm0 + xi], h0_m1 = base[o_rm1 + xi];
        float h0_p0 = base[o_rp0 + xi], h0_p1 = base[o_rp1 + xi];

        float t0 = lerp1(hm_m0, hm_m1, fm);
        float t1 = hm_0;
        float t2 = lerp1(hm_p0, hm_p1, fp);
        float t3 = lerp1(h0_m0, h0_m1, fm);
        float t4 = lerp1(h0_p0, h0_p1, fp);
        float t5 = lerp1(hp_m0, hp_m1, fm);
        float t6 = hp_0;
        float t7 = lerp1(hp_p0, hp_p1, fp);

        float su = 0.25f * (t5 + t7 - t0 - t2) + 0.5f * (t6 - t1);
        float sv = 0.25f * (t2 + t7 - t0 - t5) + 0.5f * (t4 - t3);

        float l2 = (c == 0) ? 10000.f : 1.f;
        oxx = fmaf(l2 * su, su, oxx);
        oyy = fmaf(l2 * sv, sv, oyy);
        oxy = fmaf(l2 * su, sv, oxy);
    }

    int pix = (y << 10) | xi;
    Ob[pix]             = oxx;
    Ob[PLANE + pix]     = oyy;
    Ob[2 * PLANE + pix] = oxy;
}

template<int N>
__device__ __forceinline__ void acc(float (&arr)[N], int k, float val) {
    if (k >= 0 && k < N) arr[k] += val;   // k constant after unroll
}

// Persistent fast block: covers cols x0..x0+63, bands band0..band0+3.
// Double-buffered; counted vmcnt keeps next-tile loads in flight across
// the raw barrier. Per channel: batch-load ALL window taps to registers
// (one lgkm region), then pure-VALU accumulate. Store mask
// (x>IP && x<1023-IP && y>IP) excludes clamp-wrong px (border slice).
template<int IP>
__device__ void fast_tiles(const float* __restrict__ Xb, float* __restrict__ Ob,
                           float fp, float fm, int x0, int band0,
                           int tx, int ty, int tid, float* smem)
{
    constexpr int LROWS = TROWS + 2 * IP + 2;   // staged rows per channel
    constexpr int RW    = ROWS + 2 * IP + 2;    // window rows per thread
    constexpr int NG    = 3 * LROWS * 18;       // float4 groups per tile
    constexpr int ITERS = (NG + 255) / 256;     // copies per thread (uniform)

    int x = x0 + tx;

    // Exec-uniform staging: every thread issues exactly ITERS copies.
    // Clamped tail re-loads group NG-1; HW writes LDS linearly, so tail
    // junk lands in positions NG..ITERS*256-1 -> the 1024-float pad.
    auto stage = [&](float* buf, int y0) {
        #pragma unroll
        for (int it = 0; it < ITERS; ++it) {
            int g    = min(it * 256 + tid, NG - 1);
            int row  = g / 18;
            int grp  = g - row * 18;
            int c    = row / LROWS;
            int lrow = row - c * LROWS;
            int gr   = min(max(y0 - IP - 1 + lrow, 0), H_ - 1);
            int gc   = min(max(x0 - 4 + grp * 4, 0), W_ - 4);
            async_copy16(Xb + ((size_t)c << 20) + (gr << 10) + gc,
                         buf + g * 4);
        }
    };

    stage(smem,         (band0 + 0) * TROWS);   // tile 0 -> buf0
    stage(smem + BUFSZ, (band0 + 1) * TROWS);   // tile 1 -> buf1

    #pragma unroll
    for (int t = 0; t < NTILES; ++t) {
        float* buf = smem + (t & 1) * BUFSZ;
        int y0 = (band0 + t) * TROWS;

        // Counted wait: newest ITERS vmem ops = tile t+1's staging (or,
        // at t>=NTILES-2, >=15 unmasked stores from tile t-1).
        if constexpr (ITERS >= 9) asm volatile("s_waitcnt vmcnt(9)" ::: "memory");
        else                      asm volatile("s_waitcnt vmcnt(8)" ::: "memory");
        __builtin_amdgcn_s_barrier();   // all waves' tile-t loads landed

        float oxx[ROWS], oyy[ROWS], oxy[ROWS];
        #pragma unroll
        for (int k = 0; k < ROWS; ++k) { oxx[k] = 0.f; oyy[k] = 0.f; oxy[k] = 0.f; }

        // thread's LDS read base: window row w of channel c at LDS row
        // c*LROWS + ty*ROWS + w; col of global col g is g-(x0-4); a0 at
        // col x-IP-1 -> tx + 3 - IP.
        const float* spb = buf + (ty * ROWS) * LSTRIDE + tx + (3 - IP);

        #pragma unroll
        for (int c = 0; c < 3; ++c) {
            const float* sp = spb + c * (LROWS * LSTRIDE);

            // ---- phase 1: batch-load ALL taps (one lgkm region, deep MLP)
            float vv[RW][5];
            #pragma unroll
            for (int w = 0; w < RW; ++w) {
                vv[w][0] = sp[w * LSTRIDE];
                vv[w][1] = sp[w * LSTRIDE + 1];
                vv[w][2] = sp[w * LSTRIDE + IP + 1];
                vv[w][3] = sp[w * LSTRIDE + 2 * IP + 1];
                vv[w][4] = sp[w * LSTRIDE + 2 * IP + 2];
            }

            // ---- phase 2: pure-VALU accumulate (identical math)
            float su[ROWS], sv[ROWS];
            #pragma unroll
            for (int k = 0; k < ROWS; ++k) { su[k] = 0.f; sv[k] = 0.f; }

            #pragma unroll
            for (int w = 0; w < RW; ++w) {
                float a0 = vv[w][0];
                float a1 = vv[w][1];
                float cc = vv[w][2];
                float b0 = vv[w][3];
                float b1 = vv[w][4];
                float hm = lerp1(a0, a1, fm);
                float hp = lerp1(b0, b1, fp);
                float q  = hp - hm;
                float A  = 0.25f * q;
                float hq = 0.5f  * q;
                float Bv = fmaf(0.25f, hm + hp, 0.5f * cc);
                float fpA = fp * A,  fmA = fm * A;
                float fpB = fp * Bv, fmB = fm * Bv;

                acc(su, w,              fpA);
                acc(su, w - 1,          fmA);
                acc(su, w - IP - 1,     hq);
                acc(su, w - 2*IP - 1,   fmA);
                acc(su, w - 2*IP - 2,   fpA);
                acc(sv, w,             -fpB);
                acc(sv, w - 1,         -fmB);
                acc(sv, w - 2*IP - 1,   fmB);
                acc(sv, w - 2*IP - 2,   fpB);
            }

            float l2 = (c == 0) ? 10000.f : 1.f;
            #pragma unroll
            for (int k = 0; k < ROWS; ++k) {
                oxx[k] = fmaf(l2 * su[k], su[k], oxx[k]);
                oyy[k] = fmaf(l2 * sv[k], sv[k], oyy[k]);
                oxy[k] = fmaf(l2 * su[k], sv[k], oxy[k]);
            }
        }

        // scatter stores (verified R8-R13 pattern); >=15 per wave keeps
        // the t>=NTILES-2 vmcnt bound valid.
        bool okx = (x > IP) && (x < W_ - 1 - IP);
        int Y = y0 + ty * ROWS;
        #pragma unroll
        for (int k = 0; k < ROWS; ++k) {
            int y = Y + k;
            if (okx && y > IP) {
                int pix = (y << 10) | x;
                Ob[pix]             = oxx[k];
                Ob[PLANE + pix]     = oyy[k];
                Ob[2 * PLANE + pix] = oxy[k];
            }
        }

        asm volatile("s_waitcnt lgkmcnt(0)" ::: "memory");
        __builtin_amdgcn_s_barrier();   // all waves done reading buf
        if (t + 2 < NTILES)
            stage(buf, (band0 + t + 2) * TROWS);   // refill just-freed buf
    }
}

// block (64,4). grid = (16, 9, 4): y==0 border slice (first), then 8
// persistent groups of 4 bands each.
__global__ __launch_bounds__(256, 1) void st_kernel(
    const float* __restrict__ X, const float* __restrict__ S,
    float* __restrict__ O)
{
    int b  = blockIdx.z;
    const float* Xb = X + (size_t)b * 3 * PLANE;
    float*       Ob = O + (size_t)b * 3 * PLANE;
    float sg = S[b];

    int tx = threadIdx.x, ty = threadIdx.y;
    int tid = ty * 64 + tx;

    if (blockIdx.y == 0) {
        // Border slice, dispatched first so its gather-heavy blocks
        // overlap under the fast phase. x in {0,1,2,1021,1022,1023} all
        // y (6144 px) plus y in {0,1,2} all x (3072 px). 16*256 = 4096
        // threads -> 3 iters.
        int t = blockIdx.x * 256 + tid;
        #pragma unroll
        for (int it = 0; it < 3; ++it) {
            int pidx = t + it * 4096;
            if (pidx < 6144) {
                int yy = pidx / 6;
                int cc = pidx - yy * 6;
                int xx = (cc < 3) ? cc : (W_ - 6 + cc);
                slow_pixel(Xb, Ob, sg, xx, yy);
            } else if (pidx < 9216) {
                int p2 = pidx - 6144;
                slow_pixel(Xb, Ob, sg, p2 & 1023, p2 >> 10);
            }
        }
        return;
    }

    int x0    = blockIdx.x * TCOLS;
    int band0 = (blockIdx.y - 1) * NTILES;

    int ipv = (int)floorf(sg);
    int imv = (int)floorf(-sg);
    bool sig_ok = (imv == -ipv - 1) && ipv >= 0 && ipv <= 2;  // block-uniform
    float fp = sg - (float)ipv;
    float fm = 1.0f - fp;

    // 2 buffers x (3ch x 38 rows x 72 cols + 1024-float staging pad)
    // = 73856 B -> 2 blocks/CU (LDS-capped regardless of VGPR).
    __shared__ __align__(16) float smem[2 * BUFSZ];

    if (sig_ok) {
        switch (ipv) {
            case 0:  fast_tiles<0>(Xb, Ob, fp, fm, x0, band0, tx, ty, tid, smem); break;
            case 1:  fast_tiles<1>(Xb, Ob, fp, fm, x0, band0, tx, ty, tid, smem); break;
            default: fast_tiles<2>(Xb, Ob, fp, fm, x0, band0, tx, ty, tid, smem); break;
        }
    } else {
        for (int t = 0; t < NTILES; ++t)
            for (int k = 0; k < ROWS; ++k)
                slow_pixel(Xb, Ob, sg, x0 + tx,
                           (band0 + t) * TROWS + ty * ROWS + k);
    }
}

extern "C" void kernel_launch(void* const* d_in, const int* in_sizes, int n_in,
                              void* d_out, int out_size, void* d_ws, size_t ws_size,
                              hipStream_t stream) {
    const float* x     = (const float*)d_in[0];
    const float* sigma = (const float*)d_in[1];
    float* out = (float*)d_out;

    dim3 grid(W_ / TCOLS, H_ / TROWS / NTILES + 1, 4), block(64, 4);
    hipLaunchKernelGGL(st_kernel, grid, block, 0, stream, x, sigma, out);
}

// Round 9
// 109.051 us; speedup vs baseline: 1.0376x; 1.0376x over previous
//
#include <hip/hip_runtime.h>

// StructureTensorEffect: B=4, C=3, H=W=1024, fp32.
// Round 15: kill the x-border gather path. The decisive correlation
// across R9-R14: st_kernel ~= 33 + 2.85 * (border slow_pixel iters/thread)
// -- 3 iters -> 41.5 (R9/R13/R14), 5 -> 45.7 (R11), 9 -> 58.6 (R10).
// Every fast-path experiment (staging, vmcnt pipeline, reg-MLP, stores)
// was null BECAUSE the border slice is the critical path: the 6-px-wide
// x-border columns make each of slow_pixel's 72 loads touch ~11 distinct
// 4KB-strided rows (~20 transactions/instr) with tiny in-flight MLP ->
// ~2.85us per serial pixel-iteration, ~41us total for the straggler
// blocks, while fast blocks drain in ~33 (explains VALUBusy 21% time-avg
// and occupancy ~21%). This round: x-border px (6 cols x 1024 rows)
// move to LDS-staged border-column tiles -- 16 blocks/batch stage an
// 8-col x 134-row x 3-ch window (13KB) with coalesced global_load_lds,
// then compute each px EXACTLY (slow_pixel algebra verbatim, clamps in
// global space; LDS slot s holds row clamp(y0-3+s) so slot r-y0+3 ==
// row r -- exact for ALL y incl. top). The y-border rows (y in {0,1,2},
// x-coalesced gathers, already wave-friendly) keep slow_pixel with 12
// dedicated 1-iter blocks. Fast path = R14 verbatim (persistent 4-band
// blocks, counted-vmcnt double-buffered staging, reg-batched LDS reads).
// Predicted: st 41.5 -> ~33us (the fit's intercept = fast floor).

#define W_ 1024
#define H_ 1024
#define PLANE (1 << 20)
#define TCOLS 64
#define TROWS 32
#define ROWS 8
#define LSTRIDE 72     // staged cols: x0-4 .. x0+67 (18 float4 groups)
#define NTILES 4       // tiles (y-bands) per persistent block
#define BUFSZ 9232     // floats: 3*38*72 = 8208 (worst-case IP=2) + 1024 pad

#define BX_ROWS 128    // rows per x-border block
#define BX_SLOTS 134   // BX_ROWS + 6 staged rows
#define BX_CH 1072     // BX_SLOTS * 8 floats per channel
#define BX_NG 804      // 3 * BX_SLOTS * 2 float4 groups

__device__ __forceinline__ float lerp1(float a, float b, float f) {
    return fmaf(f, b - a, a);
}

// async 16B global->LDS copy (gfx950). Dest must be linear in lane order.
__device__ __forceinline__ void async_copy16(const float* g, float* s) {
    __builtin_amdgcn_global_load_lds(
        (const __attribute__((address_space(1))) unsigned int*)g,
        (__attribute__((address_space(3))) unsigned int*)s,
        16, 0, 0);
}

// Exact per-pixel reference path (any sigma, any border) — verified R1-R14.
__device__ void slow_pixel(const float* __restrict__ Xb, float* __restrict__ Ob,
                           float sg, int xi, int y)
{
    float imf = floorf(-sg), ipf = floorf(sg);
    float fm  = -sg - imf;
    float fp  =  sg - ipf;
    int   im  = (int)imf, ip = (int)ipf;

    int cm0 = min(max(xi + im, 0), W_ - 1), cm1 = min(cm0 + 1, W_ - 1);
    int cp0 = min(max(xi + ip, 0), W_ - 1), cp1 = min(cp0 + 1, W_ - 1);
    int rm0 = min(max(y + im, 0), H_ - 1),  rm1 = min(rm0 + 1, H_ - 1);
    int rp0 = min(max(y + ip, 0), H_ - 1),  rp1 = min(rp0 + 1, H_ - 1);

    int o_rm0 = rm0 << 10, o_rm1 = rm1 << 10;
    int o_rp0 = rp0 << 10, o_rp1 = rp1 << 10;
    int o_r0  = y   << 10;

    float oxx = 0.f, oyy = 0.f, oxy = 0.f;

    #pragma unroll
    for (int c = 0; c < 3; ++c) {
        const float* base = Xb + ((size_t)c << 20);

        float hm_m0 = lerp1(base[o_rm0 + cm0], base[o_rm0 + cm1], fm);
        float hm_m1 = lerp1(base[o_rm1 + cm0], base[o_rm1 + cm1], fm);
        float hm_0  = lerp1(base[o_r0  + cm0], base[o_r0  + cm1], fm);
        float hm_p0 = lerp1(base[o_rp0 + cm0], base[o_rp0 + cm1], fm);
        float hm_p1 = lerp1(base[o_rp1 + cm0], base[o_rp1 + cm1], fm);
        float hp_m0 = lerp1(base[o_rm0 + cp0], base[o_rm0 + cp1], fp);
        float hp_m1 = lerp1(base[o_rm1 + cp0], base[o_rm1 + cp1], fp);
        float hp_0  = lerp1(base[o_r0  + cp0], base[o_r0  + cp1], fp);
        float hp_p0 = lerp1(base[o_rp0 + cp0], base[o_rp0 + cp1], fp);
        float hp_p1 = lerp1(base[o_rp1 + cp0], base[o_rp1 + cp1], fp);
        float h0_m0 = base[o_rm0 + xi], h0_m1 = base[o_rm1 + xi];
        float h0_p0 = base[o_rp0 + xi], h0_p1 = base[o_rp1 + xi];

        float t0 = lerp1(hm_m0, hm_m1, fm);
        float t1 = hm_0;
        float t2 = lerp1(hm_p0, hm_p1, fp);
        float t3 = lerp1(h0_m0, h0_m1, fm);
        float t4 = lerp1(h0_p0, h0_p1, fp);
        float t5 = lerp1(hp_m0, hp_m1, fm);
        float t6 = hp_0;
        float t7 = lerp1(hp_p0, hp_p1, fp);

        float su = 0.25f * (t5 + t7 - t0 - t2) + 0.5f * (t6 - t1);
        float sv = 0.25f * (t2 + t7 - t0 - t5) + 0.5f * (t4 - t3);

        float l2 = (c == 0) ? 10000.f : 1.f;
        oxx = fmaf(l2 * su, su, oxx);
        oyy = fmaf(l2 * sv, sv, oyy);
        oxy = fmaf(l2 * su, sv, oxy);
    }

    int pix = (y << 10) | xi;
    Ob[pix]             = oxx;
    Ob[PLANE + pix]     = oyy;
    Ob[2 * PLANE + pix] = oxy;
}

// x-border tile: stage 8 cols (left 0..7 or right 1016..1023) x 134
// clamped rows x 3 channels into LDS (coalesced 16B copies), then
// compute the 3 border columns exactly: slow_pixel algebra with all
// clamps in GLOBAL index space; LDS slot s holds row clamp(y0b-3+s),
// so for any requested row r in [0,1023], slot r-y0b+3 holds row r.
template<int IP>
__device__ void border_x_tile(const float* __restrict__ Xb, float* __restrict__ Ob,
                              float fp, float fm, int side, int y0b,
                              int tid, float* smem)
{
    const int cb = side ? (W_ - 8) : 0;
    constexpr int im = -IP - 1, ip = IP;

    // ---- stage: 3 full iterations + guarded tail (36 lanes of wave 12)
    #pragma unroll
    for (int it = 0; it < 3; ++it) {
        int g   = it * 256 + tid;
        int ch  = g / 268;
        int rem = g - ch * 268;
        int slot = rem >> 1, grp = rem & 1;
        int rr  = min(max(y0b - 3 + slot, 0), H_ - 1);
        async_copy16(Xb + ((size_t)ch << 20) + (rr << 10) + cb + grp * 4,
                     smem + g * 4);
    }
    {
        int g = 768 + tid;
        if (g < BX_NG) {
            int ch  = g / 268;
            int rem = g - ch * 268;
            int slot = rem >> 1, grp = rem & 1;
            int rr  = min(max(y0b - 3 + slot, 0), H_ - 1);
            async_copy16(Xb + ((size_t)ch << 20) + (rr << 10) + cb + grp * 4,
                         smem + g * 4);
        }
    }
    __syncthreads();   // vmcnt(0) drain + barrier

    // ---- compute: 3 cols x 128 rows = 384 px, 256 threads, 2 iters
    #pragma unroll
    for (int it = 0; it < 2; ++it) {
        int p = it * 256 + tid;
        if (p < 3 * BX_ROWS) {
            int r   = p / 3;
            int cc_ = p - r * 3;
            int y   = y0b + r;
            int xi  = cb + (side ? 5 + cc_ : cc_);   // 0..2 or 1021..1023

            int cm0 = min(max(xi + im, 0), W_ - 1), cm1 = min(cm0 + 1, W_ - 1);
            int cp0 = min(max(xi + ip, 0), W_ - 1), cp1 = min(cp0 + 1, W_ - 1);
            int rm0 = min(max(y + im, 0), H_ - 1),  rm1 = min(rm0 + 1, H_ - 1);
            int rp0 = min(max(y + ip, 0), H_ - 1),  rp1 = min(rp0 + 1, H_ - 1);

            int s_m0 = (rm0 - y0b + 3) << 3, s_m1 = (rm1 - y0b + 3) << 3;
            int s_p0 = (rp0 - y0b + 3) << 3, s_p1 = (rp1 - y0b + 3) << 3;
            int s_0  = (y   - y0b + 3) << 3;
            int lm0 = cm0 - cb, lm1 = cm1 - cb;
            int lp0 = cp0 - cb, lp1 = cp1 - cb;
            int lxi = xi - cb;

            float oxx = 0.f, oyy = 0.f, oxy = 0.f;
            #pragma unroll
            for (int c = 0; c < 3; ++c) {
                const float* base = smem + c * BX_CH;

                float hm_m0 = lerp1(base[s_m0 + lm0], base[s_m0 + lm1], fm);
                float hm_m1 = lerp1(base[s_m1 + lm0], base[s_m1 + lm1], fm);
                float hm_0  = lerp1(base[s_0  + lm0], base[s_0  + lm1], fm);
                float hm_p0 = lerp1(base[s_p0 + lm0], base[s_p0 + lm1], fm);
                float hm_p1 = lerp1(base[s_p1 + lm0], base[s_p1 + lm1], fm);
                float hp_m0 = lerp1(base[s_m0 + lp0], base[s_m0 + lp1], fp);
                float hp_m1 = lerp1(base[s_m1 + lp0], base[s_m1 + lp1], fp);
                float hp_0  = lerp1(base[s_0  + lp0], base[s_0  + lp1], fp);
                float hp_p0 = lerp1(base[s_p0 + lp0], base[s_p0 + lp1], fp);
                float hp_p1 = lerp1(base[s_p1 + lp0], base[s_p1 + lp1], fp);
                float h0_m0 = base[s_m0 + lxi], h0_m1 = base[s_m1 + lxi];
                float h0_p0 = base[s_p0 + lxi], h0_p1 = base[s_p1 + lxi];

                float t0 = lerp1(hm_m0, hm_m1, fm);
                float t1 = hm_0;
                float t2 = lerp1(hm_p0, hm_p1, fp);
                float t3 = lerp1(h0_m0, h0_m1, fm);
                float t4 = lerp1(h0_p0, h0_p1, fp);
                float t5 = lerp1(hp_m0, hp_m1, fm);
                float t6 = hp_0;
                float t7 = lerp1(hp_p0, hp_p1, fp);

                float su = 0.25f * (t5 + t7 - t0 - t2) + 0.5f * (t6 - t1);
                float sv = 0.25f * (t2 + t7 - t0 - t5) + 0.5f * (t4 - t3);

                float l2 = (c == 0) ? 10000.f : 1.f;
                oxx = fmaf(l2 * su, su, oxx);
                oyy = fmaf(l2 * sv, sv, oyy);
                oxy = fmaf(l2 * su, sv, oxy);
            }

            int pix = (y << 10) | xi;
            Ob[pix]             = oxx;
            Ob[PLANE + pix]     = oyy;
            Ob[2 * PLANE + pix] = oxy;
        }
    }
}

template<int N>
__device__ __forceinline__ void acc(float (&arr)[N], int k, float val) {
    if (k >= 0 && k < N) arr[k] += val;   // k constant after unroll
}

// Persistent fast block: covers cols x0..x0+63, bands band0..band0+3.
// Double-buffered; counted vmcnt keeps next-tile loads in flight across
// the raw barrier. Per channel: batch-load ALL window taps to registers
// (one lgkm region), then pure-VALU accumulate. Store mask
// (x>IP && x<1023-IP && y>IP) excludes clamp-wrong px (border paths).
template<int IP>
__device__ void fast_tiles(const float* __restrict__ Xb, float* __restrict__ Ob,
                           float fp, float fm, int x0, int band0,
                           int tx, int ty, int tid, float* smem)
{
    constexpr int LROWS = TROWS + 2 * IP + 2;   // staged rows per channel
    constexpr int RW    = ROWS + 2 * IP + 2;    // window rows per thread
    constexpr int NG    = 3 * LROWS * 18;       // float4 groups per tile
    constexpr int ITERS = (NG + 255) / 256;     // copies per thread (uniform)

    int x = x0 + tx;

    // Exec-uniform staging: every thread issues exactly ITERS copies.
    // Clamped tail re-loads group NG-1; HW writes LDS linearly, so tail
    // junk lands in positions NG..ITERS*256-1 -> the 1024-float pad.
    auto stage = [&](float* buf, int y0) {
        #pragma unroll
        for (int it = 0; it < ITERS; ++it) {
            int g    = min(it * 256 + tid, NG - 1);
            int row  = g / 18;
            int grp  = g - row * 18;
            int c    = row / LROWS;
            int lrow = row - c * LROWS;
            int gr   = min(max(y0 - IP - 1 + lrow, 0), H_ - 1);
            int gc   = min(max(x0 - 4 + grp * 4, 0), W_ - 4);
            async_copy16(Xb + ((size_t)c << 20) + (gr << 10) + gc,
                         buf + g * 4);
        }
    };

    stage(smem,         (band0 + 0) * TROWS);   // tile 0 -> buf0
    stage(smem + BUFSZ, (band0 + 1) * TROWS);   // tile 1 -> buf1

    #pragma unroll
    for (int t = 0; t < NTILES; ++t) {
        float* buf = smem + (t & 1) * BUFSZ;
        int y0 = (band0 + t) * TROWS;

        // Counted wait: newest ITERS vmem ops = tile t+1's staging (or,
        // at t>=NTILES-2, >=15 unmasked stores from tile t-1).
        if constexpr (ITERS >= 9) asm volatile("s_waitcnt vmcnt(9)" ::: "memory");
        else                      asm volatile("s_waitcnt vmcnt(8)" ::: "memory");
        __builtin_amdgcn_s_barrier();   // all waves' tile-t loads landed

        float oxx[ROWS], oyy[ROWS], oxy[ROWS];
        #pragma unroll
        for (int k = 0; k < ROWS; ++k) { oxx[k] = 0.f; oyy[k] = 0.f; oxy[k] = 0.f; }

        // thread's LDS read base: window row w of channel c at LDS row
        // c*LROWS + ty*ROWS + w; col of global col g is g-(x0-4); a0 at
        // col x-IP-1 -> tx + 3 - IP.
        const float* spb = buf + (ty * ROWS) * LSTRIDE + tx + (3 - IP);

        #pragma unroll
        for (int c = 0; c < 3; ++c) {
            const float* sp = spb + c * (LROWS * LSTRIDE);

            // ---- phase 1: batch-load ALL taps (one lgkm region, deep MLP)
            float vv[RW][5];
            #pragma unroll
            for (int w = 0; w < RW; ++w) {
                vv[w][0] = sp[w * LSTRIDE];
                vv[w][1] = sp[w * LSTRIDE + 1];
                vv[w][2] = sp[w * LSTRIDE + IP + 1];
                vv[w][3] = sp[w * LSTRIDE + 2 * IP + 1];
                vv[w][4] = sp[w * LSTRIDE + 2 * IP + 2];
            }

            // ---- phase 2: pure-VALU accumulate (identical math)
            float su[ROWS], sv[ROWS];
            #pragma unroll
            for (int k = 0; k < ROWS; ++k) { su[k] = 0.f; sv[k] = 0.f; }

            #pragma unroll
            for (int w = 0; w < RW; ++w) {
                float a0 = vv[w][0];
                float a1 = vv[w][1];
                float cc = vv[w][2];
                float b0 = vv[w][3];
                float b1 = vv[w][4];
                float hm = lerp1(a0, a1, fm);
                float hp = lerp1(b0, b1, fp);
                float q  = hp - hm;
                float A  = 0.25f * q;
                float hq = 0.5f  * q;
                float Bv = fmaf(0.25f, hm + hp, 0.5f * cc);
                float fpA = fp * A,  fmA = fm * A;
                float fpB = fp * Bv, fmB = fm * Bv;

                acc(su, w,              fpA);
                acc(su, w - 1,          fmA);
                acc(su, w - IP - 1,     hq);
                acc(su, w - 2*IP - 1,   fmA);
                acc(su, w - 2*IP - 2,   fpA);
                acc(sv, w,             -fpB);
                acc(sv, w - 1,         -fmB);
                acc(sv, w - 2*IP - 1,   fmB);
                acc(sv, w - 2*IP - 2,   fpB);
            }

            float l2 = (c == 0) ? 10000.f : 1.f;
            #pragma unroll
            for (int k = 0; k < ROWS; ++k) {
                oxx[k] = fmaf(l2 * su[k], su[k], oxx[k]);
                oyy[k] = fmaf(l2 * sv[k], sv[k], oyy[k]);
                oxy[k] = fmaf(l2 * su[k], sv[k], oxy[k]);
            }
        }

        // scatter stores (verified R8-R14 pattern); >=15 per wave keeps
        // the t>=NTILES-2 vmcnt bound valid.
        bool okx = (x > IP) && (x < W_ - 1 - IP);
        int Y = y0 + ty * ROWS;
        #pragma unroll
        for (int k = 0; k < ROWS; ++k) {
            int y = Y + k;
            if (okx && y > IP) {
                int pix = (y << 10) | x;
                Ob[pix]             = oxx[k];
                Ob[PLANE + pix]     = oyy[k];
                Ob[2 * PLANE + pix] = oxy[k];
            }
        }

        asm volatile("s_waitcnt lgkmcnt(0)" ::: "memory");
        __builtin_amdgcn_s_barrier();   // all waves done reading buf
        if (t + 2 < NTILES)
            stage(buf, (band0 + t + 2) * TROWS);   // refill just-freed buf
    }
}

// block (64,4). grid = (16, 10, 4):
//   y==0: 16 x-border tiles (side = x&1, 128-row chunk = x>>1)
//   y==1: 12 y-border-row blocks (y in {0,1,2}, all x), 4 idle
//   y>=2: 8 persistent fast groups of 4 bands each
__global__ __launch_bounds__(256, 1) void st_kernel(
    const float* __restrict__ X, const float* __restrict__ S,
    float* __restrict__ O)
{
    int b  = blockIdx.z;
    const float* Xb = X + (size_t)b * 3 * PLANE;
    float*       Ob = O + (size_t)b * 3 * PLANE;
    float sg = S[b];

    int tx = threadIdx.x, ty = threadIdx.y;
    int tid = ty * 64 + tx;

    int ipv = (int)floorf(sg);
    int imv = (int)floorf(-sg);
    bool sig_ok = (imv == -ipv - 1) && ipv >= 0 && ipv <= 2;  // block-uniform
    float fp = sg - (float)ipv;
    float fm = 1.0f - fp;

    // 2 buffers x (3ch x 38 rows x 72 cols + 1024-float staging pad)
    // = 73856 B -> 2 blocks/CU. Border tiles reuse the first ~13 KB.
    __shared__ __align__(16) float smem[2 * BUFSZ];

    if (blockIdx.y == 0) {
        int side = blockIdx.x & 1;
        int y0b  = (blockIdx.x >> 1) * BX_ROWS;
        if (sig_ok) {
            switch (ipv) {
                case 0:  border_x_tile<0>(Xb, Ob, fp, fm, side, y0b, tid, smem); break;
                case 1:  border_x_tile<1>(Xb, Ob, fp, fm, side, y0b, tid, smem); break;
                default: border_x_tile<2>(Xb, Ob, fp, fm, side, y0b, tid, smem); break;
            }
        } else {
            for (int it = 0; it < 2; ++it) {
                int p = it * 256 + tid;
                if (p < 3 * BX_ROWS) {
                    int r = p / 3, cc = p - r * 3;
                    int xi = side ? 1021 + cc : cc;
                    slow_pixel(Xb, Ob, sg, xi, y0b + r);
                }
            }
        }
        return;
    }

    if (blockIdx.y == 1) {
        // y-border rows 0..2, all x: 3072 px, 12 blocks x 256 threads,
        // lanes consecutive in x -> coalesced gathers.
        int p = blockIdx.x * 256 + tid;
        if (p < 3072) slow_pixel(Xb, Ob, sg, p & 1023, p >> 10);
        return;
    }

    int x0    = blockIdx.x * TCOLS;
    int band0 = (blockIdx.y - 2) * NTILES;

    if (sig_ok) {
        switch (ipv) {
            case 0:  fast_tiles<0>(Xb, Ob, fp, fm, x0, band0, tx, ty, tid, smem); break;
            case 1:  fast_tiles<1>(Xb, Ob, fp, fm, x0, band0, tx, ty, tid, smem); break;
            default: fast_tiles<2>(Xb, Ob, fp, fm, x0, band0, tx, ty, tid, smem); break;
        }
    } else {
        for (int t = 0; t < NTILES; ++t)
            for (int k = 0; k < ROWS; ++k)
                slow_pixel(Xb, Ob, sg, x0 + tx,
                           (band0 + t) * TROWS + ty * ROWS + k);
    }
}

extern "C" void kernel_launch(void* const* d_in, const int* in_sizes, int n_in,
                              void* d_out, int out_size, void* d_ws, size_t ws_size,
                              hipStream_t stream) {
    const float* x     = (const float*)d_in[0];
    const float* sigma = (const float*)d_in[1];
    float* out = (float*)d_out;

    dim3 grid(W_ / TCOLS, H_ / TROWS / NTILES + 2, 4), block(64, 4);
    hipLaunchKernelGGL(st_kernel, grid, block, 0, stream, x, sigma, out);
}